// Round 5
// baseline (1827.692 us; speedup 1.0000x reference)
//
#include <hip/hip_runtime.h>

typedef unsigned short ushort_t;
typedef unsigned int uint_t;
typedef __attribute__((ext_vector_type(8))) short short8;
typedef __attribute__((ext_vector_type(4))) float f32x4;
typedef __attribute__((ext_vector_type(4))) uint_t uint4a;
typedef __attribute__((ext_vector_type(2))) uint_t uint2a;

#define Tn 256
#define Bn 64
#define Hn 512
#define En 256
#define G4 2048
#define Nt 6

// ---------- helpers ----------
__device__ inline ushort_t f2bf(float f) {
    uint_t u = __float_as_uint(f);
    uint_t r = u + 0x7FFFu + ((u >> 16) & 1u);
    return (ushort_t)(r >> 16);
}
__device__ inline float bf2f(ushort_t h) { return __uint_as_float(((uint_t)h) << 16); }
__device__ inline float sigm(float x) { return 1.f / (1.f + __expf(-x)); }
__device__ inline float tanh_(float x) { return 2.f / (1.f + __expf(-2.f * x)) - 1.f; }

// device-scope (sc1) memory ops: bypass L1+L2, coherence point = Infinity Cache.
__device__ inline uint4a gload16_sc1(const void* p) {
    uint4a r;
    asm volatile("global_load_dwordx4 %0, %1, off sc1" : "=v"(r) : "v"(p) : "memory");
    return r;
}
__device__ inline void gstore8_sc1(void* p, uint2a v) {
    asm volatile("global_store_dwordx2 %0, %1, off sc1" :: "v"(p), "v"(v) : "memory");
}

// ---------- ws layout (bytes) ----------
#define OFF_XBF    0u               // 16384*256 bf16            = 8,388,608
#define OFF_WIH    8388608u         // 2*2048*256 bf16           = 2,097,152
#define OFF_WHH    10485760u        // 2*2048*512 bf16           = 4,194,304
#define OFF_HP     14680064u        // 4 grp * 2 buf * 8192 * 8B = 524,288  (tagged h pairs)
#define OFF_HS     15204352u        // 16384*1024 bf16           = 33,554,432  (end 48,758,784)
#define OFF_EMIS   8388608u         // overlays WIH: dead after lstm_kernel; prep rewrites each call

// ---------- kernel 1: prep ----------
__global__ void prep_kernel(const int* __restrict__ sent, const float* __restrict__ embed,
                            const float* __restrict__ Wihf, const float* __restrict__ Whhf,
                            const float* __restrict__ Wihb, const float* __restrict__ Whhb,
                            const float* __restrict__ h0, float* __restrict__ out,
                            ushort_t* __restrict__ x_bf, ushort_t* __restrict__ Wih_bf,
                            ushort_t* __restrict__ Whh_bf, uint2a* __restrict__ hpair) {
    long i = (long)blockIdx.x * 256 + threadIdx.x;
    const long n0 = 2097152, n1 = 1048576, n2 = 4194304, n3 = 32768;
    if (i < n0) {  // Whh cast: [dir][2048][512]
        long d = i >> 20, r = i & 1048575;
        const float* W = d ? Whhb : Whhf;
        Whh_bf[i] = f2bf(W[r]);
        return;
    }
    i -= n0;
    if (i < n1) {  // Wih cast: [dir][2048][256]
        long d = i >> 19, r = i & 524287;
        const float* W = d ? Wihb : Wihf;
        Wih_bf[(d << 19) + r] = f2bf(W[r]);
        return;
    }
    i -= n1;
    if (i < n2) {  // x gather: row = t*B+b
        long row = i >> 8, e = i & 255;
        int tok = sent[row];
        x_bf[i] = f2bf(embed[(size_t)tok * 256 + e]);
        return;
    }
    i -= n2;
    if (i < n3) {  // h0 -> tagged pair buf0: {2xbf16, tag=0}
        long dir = i >> 14, rem = i & 16383;
        long b = rem >> 8, jw = rem & 255;
        int bh = (int)(b >> 5), bl = (int)(b & 31);
        int group = (int)(dir * 2 + bh);
        const float* hp = h0 + (size_t)dir * Bn * Hn + (size_t)b * Hn + jw * 2;
        uint2a pv;
        pv.x = (uint_t)f2bf(hp[0]) | ((uint_t)f2bf(hp[1]) << 16);
        pv.y = 0u;
        gstore8_sc1(hpair + (size_t)group * 2 * 8192 + (size_t)bl * 256 + jw, pv);
        return;
    }
    i -= n3;
    if (i == 0) { out[0] = 0.f; }
}

// ---------- kernel 2: persistent fused BiLSTM ----------
// 128 WGs: dir(2) x batch-half(2) x gate-slice(32).  256 threads.
// Cross-WG h exchange via tagged 8B pairs at IF$ (sc1) — the tag-poll IS the
// barrier; no flags, no fences, no store drains on the critical path.
__global__ void __launch_bounds__(256, 1) lstm_kernel(
    const ushort_t* __restrict__ x_bf, const ushort_t* __restrict__ Wih_bf,
    const ushort_t* __restrict__ Whh_bf, const float* __restrict__ biasf,
    const float* __restrict__ biasb, const float* __restrict__ c0,
    const int* __restrict__ mask, uint2a* __restrict__ hpair,
    ushort_t* __restrict__ hs) {

    __shared__ __align__(16) ushort_t x_s[2][32 * 264];
    __shared__ __align__(16) ushort_t h_s[32 * 520];
    __shared__ __align__(16) float gates_s[64 * 33];

    const int tid = threadIdx.x;
    const int wid = blockIdx.x;
    const int dir = wid >> 6;
    const int bh  = (wid >> 5) & 1;
    const int gs  = wid & 31;
    const int j0  = gs * 16;
    const int group = dir * 2 + bh;
    uint2a* pg = hpair + (size_t)group * 2 * 8192;   // [buf][bl(32)][jw(256)]

    const int lane = tid & 63;
    const int wv = tid >> 6;            // wave = gate type (i,f,g,o)
    const int qo = (lane >> 4) * 8;     // k-chunk offset in fragment
    const int ml = lane & 15;

    // persistent B fragments (W_ih: 8 ksteps, W_hh: 16 ksteps) in VGPRs
    const int grow = wv * 512 + j0 + ml;   // global gate row 0..2047
    short8 bxf[8], bhf[16];
    {
        const ushort_t* wr = Wih_bf + (size_t)dir * G4 * En + (size_t)grow * En + qo;
        #pragma unroll
        for (int ks = 0; ks < 8; ++ks) bxf[ks] = *(const short8*)(wr + ks * 32);
        const ushort_t* wr2 = Whh_bf + (size_t)dir * G4 * Hn + (size_t)grow * Hn + qo;
        #pragma unroll
        for (int ks = 0; ks < 16; ++ks) bhf[ks] = *(const short8*)(wr2 + ks * 32);
    }
    const float bv = (dir ? biasb : biasf)[grow];

    // update-phase mapping: thread -> (2 consecutive j, one batch) => one 8B pair store
    const int jp = (tid & 7) * 2;       // j pair base within slice
    const int bl = tid >> 3;            // local batch 0..31
    const int bg = bh * 32 + bl;
    float creg[2];
    #pragma unroll
    for (int r = 0; r < 2; ++r)
        creg[r] = c0[(size_t)dir * Bn * Hn + (size_t)bg * Hn + j0 + jp + r];

    const ushort_t* xbase = x_bf + (size_t)bh * 32 * En;

    // x[t0] prefetch + LDS write (buffer 0)
    uint4 xreg[4];
    {
        const int t0 = dir ? (Tn - 1) : 0;
        const uint4* g4 = (const uint4*)(xbase + (size_t)t0 * Bn * En);
        #pragma unroll
        for (int k = 0; k < 4; ++k) xreg[k] = g4[tid + k * 256];
        #pragma unroll
        for (int k = 0; k < 4; ++k) {
            int c16 = tid + k * 256;
            int row = c16 >> 5, col = c16 & 31;
            *(uint4*)&x_s[0][row * 264 + col * 8] = xreg[k];
        }
    }

    for (int s = 0; s < Tn; ++s) {
        const int t = dir ? (Tn - 1 - s) : s;
        const int cur = s & 1, nxt = cur ^ 1;
        const uint_t rtag = (uint_t)s;
        const uint2a* rb = pg + (size_t)cur * 8192;

        // phase 1: speculatively issue all 16 h-pair loads (2 pairs / 16B each)
        uint4a v[16];
        #pragma unroll
        for (int k = 0; k < 16; ++k) {
            int c = tid + (k << 8);
            v[k] = gload16_sc1(rb + (size_t)((c >> 7) * 256 + ((c & 127) << 1)));
        }
        // then x[t+1] prefetch (plain cached) + mask
        if (s < Tn - 1) {
            const int tn = dir ? (Tn - 2 - s) : (s + 1);
            const uint4* g4 = (const uint4*)(xbase + (size_t)tn * Bn * En);
            #pragma unroll
            for (int k = 0; k < 4; ++k) xreg[k] = g4[tid + k * 256];
        }
        const int mv = mask[t * Bn + bg];

        __syncthreads();   // x_s[cur] writes from prev iter complete

        // phase 2: x-part MFMAs while h loads are in flight
        f32x4 acc0, acc1;
        #pragma unroll
        for (int r = 0; r < 4; ++r) { acc0[r] = bv; acc1[r] = bv; }
        {
            const ushort_t* xr0 = &x_s[cur][ml * 264 + qo];
            const ushort_t* xr1 = &x_s[cur][(16 + ml) * 264 + qo];
            #pragma unroll
            for (int ks = 0; ks < 8; ++ks) {
                short8 a0 = *(const short8*)(xr0 + ks * 32);
                short8 a1 = *(const short8*)(xr1 + ks * 32);
                acc0 = __builtin_amdgcn_mfma_f32_16x16x32_bf16(a0, bxf[ks], acc0, 0, 0, 0);
                acc1 = __builtin_amdgcn_mfma_f32_16x16x32_bf16(a1, bxf[ks], acc1, 0, 0, 0);
            }
        }

        // phase 3: tag-poll; stage arrived pairs into LDS, re-issue stale chunks
        {
            uint_t done = 0;
            while (true) {
                #pragma unroll
                for (int k = 0; k < 16; ++k) {
                    if (!(done & (1u << k))) {
                        if (v[k].y == rtag && v[k].w == rtag) {
                            int c = tid + (k << 8);
                            int row = c >> 7, pc = c & 127;
                            uint2a hw; hw.x = v[k].x; hw.y = v[k].z;
                            *(uint2a*)&h_s[row * 520 + (pc << 2)] = hw;
                            done |= (1u << k);
                        }
                    }
                }
                if (done == 0xFFFFu) break;
                #pragma unroll
                for (int k = 0; k < 16; ++k) {
                    if (!(done & (1u << k))) {
                        int c = tid + (k << 8);
                        v[k] = gload16_sc1(rb + (size_t)((c >> 7) * 256 + ((c & 127) << 1)));
                    }
                }
            }
        }
        __syncthreads();

        // phase 4: h-part MFMAs
        {
            const ushort_t* hr0 = &h_s[ml * 520 + qo];
            const ushort_t* hr1 = &h_s[(16 + ml) * 520 + qo];
            #pragma unroll
            for (int ks = 0; ks < 16; ++ks) {
                short8 a0 = *(const short8*)(hr0 + ks * 32);
                short8 a1 = *(const short8*)(hr1 + ks * 32);
                acc0 = __builtin_amdgcn_mfma_f32_16x16x32_bf16(a0, bhf[ks], acc0, 0, 0, 0);
                acc1 = __builtin_amdgcn_mfma_f32_16x16x32_bf16(a1, bhf[ks], acc1, 0, 0, 0);
            }
        }
        {   // C layout: col=lane&15 (gate), row=(lane>>4)*4+reg (batch)
            int nl = wv * 16 + ml;
            int br = (lane >> 4) * 4;
            #pragma unroll
            for (int r = 0; r < 4; ++r) {
                gates_s[nl * 33 + br + r]      = acc0[r];
                gates_s[nl * 33 + 16 + br + r] = acc1[r];
            }
        }
        __syncthreads();

        // phase 5: write next x into the other LDS buffer
        if (s < Tn - 1) {
            #pragma unroll
            for (int k = 0; k < 4; ++k) {
                int c16 = tid + k * 256;
                int row = c16 >> 5, col = c16 & 31;
                *(uint4*)&x_s[nxt][row * 264 + col * 8] = xreg[k];
            }
        }

        // phase 6: cell update; publish tagged pair (tag = s+1) — no drain needed
        {
            ushort_t hu[2], su[2];
            #pragma unroll
            for (int r = 0; r < 2; ++r) {
                int j = jp + r;
                float iv = gates_s[j * 33 + bl];
                float fv = gates_s[(16 + j) * 33 + bl];
                float gv = gates_s[(32 + j) * 33 + bl];
                float ov = gates_s[(48 + j) * 33 + bl];
                float cn = sigm(fv) * creg[r] + sigm(iv) * tanh_(gv);
                float hn = sigm(ov) * tanh_(cn);
                float hp = bf2f(h_s[bl * 520 + j0 + j]);
                float h2, hsv;
                if (mv) { creg[r] = cn; h2 = hn; hsv = hn; }
                else    { h2 = hp; hsv = 0.f; }
                hu[r] = f2bf(h2);
                su[r] = f2bf(hsv);
            }
            uint2a pv;
            pv.x = (uint_t)hu[0] | ((uint_t)hu[1] << 16);
            pv.y = (uint_t)(s + 1);
            gstore8_sc1(pg + (size_t)nxt * 8192 + (size_t)bl * 256 + ((j0 + jp) >> 1), pv);
            __builtin_nontemporal_store(
                (uint_t)su[0] | ((uint_t)su[1] << 16),
                (uint_t*)&hs[((size_t)t * Bn + bg) * 1024 + dir * 512 + j0 + jp]);
        }
    }
}

// ---------- kernel 3: emission projection (wave per row) ----------
__global__ void emis_kernel(const ushort_t* __restrict__ hs, const float* __restrict__ Wout,
                            const float* __restrict__ bout, float* __restrict__ emis) {
    int row = blockIdx.x * 4 + (threadIdx.x >> 6);
    int lane = threadIdx.x & 63;
    const ushort_t* hr = hs + (size_t)row * 1024;
    float acc[6] = {0, 0, 0, 0, 0, 0};
    for (int kk = 0; kk < 16; ++kk) {
        int k = kk * 64 + lane;
        float h = bf2f(hr[k]);
        #pragma unroll
        for (int n = 0; n < Nt; ++n) acc[n] += h * Wout[n * 1024 + k];
    }
    #pragma unroll
    for (int n = 0; n < Nt; ++n) {
        float v = acc[n];
        #pragma unroll
        for (int off = 32; off; off >>= 1) v += __shfl_down(v, off);
        if (lane == 0) emis[row * Nt + n] = v + bout[n];
    }
}

// ---------- kernel 4: CRF LLH (one wave per batch) ----------
__global__ void crf_kernel(const int* __restrict__ tags, const int* __restrict__ mask,
                           const float* __restrict__ emis, const float* __restrict__ trans,
                           const float* __restrict__ startt, const float* __restrict__ endt,
                           float* __restrict__ out) {
    int b = blockIdx.x;
    int lane = threadIdx.x;

    // numerator partials over strided t
    float part = 0.f;
    int mc = 0;
    for (int t = lane; t < Tn; t += 64) {
        int mv = mask[t * Bn + b];
        mc += mv;
        if (t >= 1) {
            int tp = tags[(t - 1) * Bn + b], tc = tags[t * Bn + b];
            part += (trans[tp * Nt + tc] + emis[(t * Bn + b) * Nt + tc]) * (float)mv;
        }
    }
    #pragma unroll
    for (int off = 32; off; off >>= 1) {
        part += __shfl_down(part, off);
        mc += __shfl_down(mc, off);
    }
    float num = 0.f;
    if (lane == 0) {
        int t0g = tags[b];
        num = startt[t0g] + emis[b * Nt + t0g] + part;
        int last = mc - 1;
        num += endt[tags[last * Bn + b]];
    }

    // denominator: forward algorithm, lanes 0..5 hold score[j]; t-loop pipelined
    if (lane < Nt) {
        int j = lane;
        float tr[6];
        #pragma unroll
        for (int i = 0; i < Nt; ++i) tr[i] = trans[i * Nt + j];
        float score = startt[j] + emis[b * Nt + j];
        float e_nx = emis[(Bn + b) * Nt + j];
        int   m_nx = mask[Bn + b];
        for (int t = 1; t < Tn; ++t) {
            float e = e_nx;
            int mv = m_nx;
            if (t + 1 < Tn) {
                e_nx = emis[((t + 1) * Bn + b) * Nt + j];
                m_nx = mask[(t + 1) * Bn + b];
            }
            float v[6];
            float mx = -1e30f;
            #pragma unroll
            for (int i = 0; i < Nt; ++i) { v[i] = __shfl(score, i) + tr[i]; mx = fmaxf(mx, v[i]); }
            float sm = 0.f;
            #pragma unroll
            for (int i = 0; i < Nt; ++i) sm += __expf(v[i] - mx);
            float nxtv = mx + __logf(sm) + e;
            score = mv > 0 ? nxtv : score;
        }
        float fvv = score + endt[j];
        float m2 = fvv;
        #pragma unroll
        for (int i = 0; i < Nt; ++i) m2 = fmaxf(m2, __shfl(fvv, i));
        float s2 = 0.f;
        #pragma unroll
        for (int i = 0; i < Nt; ++i) s2 += __expf(__shfl(fvv, i) - m2);
        if (lane == 0) {
            float denom = m2 + __logf(s2);
            atomicAdd(out, num - denom);
        }
    }
}

extern "C" void kernel_launch(void* const* d_in, const int* in_sizes, int n_in,
                              void* d_out, int out_size, void* d_ws, size_t ws_size,
                              hipStream_t stream) {
    (void)in_sizes; (void)n_in; (void)out_size; (void)ws_size;
    const int*   sent  = (const int*)d_in[0];
    const int*   tags  = (const int*)d_in[1];
    const int*   mask  = (const int*)d_in[2];
    const float* h0    = (const float*)d_in[3];
    const float* c0    = (const float*)d_in[4];
    const float* embed = (const float*)d_in[5];
    const float* Wihf  = (const float*)d_in[6];
    const float* Whhf  = (const float*)d_in[7];
    const float* bf_   = (const float*)d_in[8];
    const float* Wihb  = (const float*)d_in[9];
    const float* Whhb  = (const float*)d_in[10];
    const float* bb_   = (const float*)d_in[11];
    const float* Wout  = (const float*)d_in[12];
    const float* bout  = (const float*)d_in[13];
    const float* trans = (const float*)d_in[14];
    const float* stt   = (const float*)d_in[15];
    const float* ent   = (const float*)d_in[16];
    float* out = (float*)d_out;
    char* ws = (char*)d_ws;

    ushort_t* x_bf   = (ushort_t*)(ws + OFF_XBF);
    ushort_t* Wih_bf = (ushort_t*)(ws + OFF_WIH);
    ushort_t* Whh_bf = (ushort_t*)(ws + OFF_WHH);
    uint2a*   hpair  = (uint2a*)(ws + OFF_HP);
    ushort_t* hs     = (ushort_t*)(ws + OFF_HS);
    float*    emis   = (float*)(ws + OFF_EMIS);

    prep_kernel<<<28801, 256, 0, stream>>>(sent, embed, Wihf, Whhf, Wihb, Whhb,
                                           h0, out, x_bf, Wih_bf, Whh_bf, hpair);
    lstm_kernel<<<128, 256, 0, stream>>>(x_bf, Wih_bf, Whh_bf, bf_, bb_, c0,
                                         mask, hpair, hs);
    emis_kernel<<<4096, 256, 0, stream>>>(hs, Wout, bout, emis);
    crf_kernel<<<64, 64, 0, stream>>>(tags, mask, emis, trans, stt, ent, out);
}

// Round 8
// 1226.520 us; speedup vs baseline: 1.4901x; 1.4901x over previous
//
#include <hip/hip_runtime.h>

typedef unsigned short ushort_t;
typedef unsigned int uint_t;
typedef __attribute__((ext_vector_type(8))) short short8;
typedef __attribute__((ext_vector_type(4))) float f32x4;
typedef __attribute__((ext_vector_type(4))) uint_t uint4a;
typedef __attribute__((ext_vector_type(2))) uint_t uint2a;

#define Tn 256
#define Bn 64
#define Hn 512
#define En 256
#define G4 2048
#define Nt 6

// ---------- helpers ----------
__device__ inline ushort_t f2bf(float f) {
    uint_t u = __float_as_uint(f);
    uint_t r = u + 0x7FFFu + ((u >> 16) & 1u);
    return (ushort_t)(r >> 16);
}
__device__ inline float bf2f(ushort_t h) { return __uint_as_float(((uint_t)h) << 16); }
__device__ inline float sigm(float x) { return 1.f / (1.f + __expf(-x)); }
__device__ inline float tanh_(float x) { return 2.f / (1.f + __expf(-2.f * x)) - 1.f; }

// device-scope (sc1) ops: bypass L1+L2, coherence point = Infinity Cache.
// !! inline-asm loads are INVISIBLE to the compiler's waitcnt pass: the
// result VGPRs are written asynchronously; ALWAYS vm_drain() before use.
__device__ inline uint4a gload16_sc1(const void* p) {
    uint4a r;
    asm volatile("global_load_dwordx4 %0, %1, off sc1" : "=v"(r) : "v"(p) : "memory");
    return r;
}
__device__ inline int gload4_sc1(const void* p) {
    int r;
    asm volatile("global_load_dword %0, %1, off sc1" : "=v"(r) : "v"(p) : "memory");
    return r;
}
__device__ inline void gstore4_sc1(void* p, uint_t v) {
    asm volatile("global_store_dword %0, %1, off sc1" :: "v"(p), "v"(v) : "memory");
}
__device__ inline void vm_drain() { asm volatile("s_waitcnt vmcnt(0)" ::: "memory"); }

// ---------- ws layout (bytes) ----------
#define OFF_XBF    0u               // 16384*256 bf16        = 8,388,608
#define OFF_WIH    8388608u         // 2*2048*256 bf16       = 2,097,152
#define OFF_WHH    10485760u        // 2*2048*512 bf16       = 4,194,304
#define OFF_HG     14680064u        // 2 dir*2 buf*64*512 bf16 = 262,144
#define OFF_HS     15204352u        // 16384*1024 bf16       = 33,554,432 (end 48,758,784)
#define OFF_BAR    48758784u        // 4 groups * 1024 ints  = 16,384
#define OFF_EMIS   8388608u         // overlays WIH (dead after lstm; prep rewrites each call)

// ---------- kernel 1: prep (4 elems/thread packed) ----------
__global__ void prep_kernel(const int* __restrict__ sent, const float* __restrict__ embed,
                            const float* __restrict__ Wihf, const float* __restrict__ Whhf,
                            const float* __restrict__ Wihb, const float* __restrict__ Whhb,
                            const float* __restrict__ h0, float* __restrict__ out,
                            ushort_t* __restrict__ x_bf, ushort_t* __restrict__ Wih_bf,
                            ushort_t* __restrict__ Whh_bf, ushort_t* __restrict__ hglob,
                            int* __restrict__ bar) {
    long i = (long)blockIdx.x * 256 + threadIdx.x;
    const long nA = 524288, nB = 262144, nC = 1048576, nD = 32768, nE = 4096;
    if (i < nA) {  // Whh cast: [dir][2048][512], 4 elems
        long e4 = i << 2;
        long d = e4 >> 20, r = e4 & 1048575;
        const float* W = d ? Whhb : Whhf;
        float4 v = *(const float4*)(W + r);
        uint2a pv;
        pv.x = (uint_t)f2bf(v.x) | ((uint_t)f2bf(v.y) << 16);
        pv.y = (uint_t)f2bf(v.z) | ((uint_t)f2bf(v.w) << 16);
        *(uint2a*)(Whh_bf + e4) = pv;
        return;
    }
    i -= nA;
    if (i < nB) {  // Wih cast: [dir][2048][256], 4 elems
        long e4 = i << 2;
        long d = e4 >> 19, r = e4 & 524287;
        const float* W = d ? Wihb : Wihf;
        float4 v = *(const float4*)(W + r);
        uint2a pv;
        pv.x = (uint_t)f2bf(v.x) | ((uint_t)f2bf(v.y) << 16);
        pv.y = (uint_t)f2bf(v.z) | ((uint_t)f2bf(v.w) << 16);
        *(uint2a*)(Wih_bf + (d << 19) + r) = pv;
        return;
    }
    i -= nB;
    if (i < nC) {  // x gather: row = t*B+b, 4 elems within one embed row
        long e4 = i << 2;
        long row = e4 >> 8, e = e4 & 255;
        int tok = sent[row];
        float4 v = *(const float4*)(embed + (size_t)tok * 256 + e);
        uint2a pv;
        pv.x = (uint_t)f2bf(v.x) | ((uint_t)f2bf(v.y) << 16);
        pv.y = (uint_t)f2bf(v.z) | ((uint_t)f2bf(v.w) << 16);
        *(uint2a*)(x_bf + e4) = pv;
        return;
    }
    i -= nC;
    if (i < nD) {  // h0 -> hglob[dir][buf0][b][k], one bf16 pair (sc1: IF$-visible)
        long dir = i >> 14, rem = i & 16383;
        long b = rem >> 8, jw = rem & 255;
        const float* hp = h0 + (size_t)dir * Bn * Hn + (size_t)b * Hn + jw * 2;
        gstore4_sc1(hglob + dir * 65536 + b * 512 + jw * 2,
                    (uint_t)f2bf(hp[0]) | ((uint_t)f2bf(hp[1]) << 16));
        return;
    }
    i -= nD;
    if (i < nE) { gstore4_sc1(&bar[i], 0u); return; }
    if (i == nE) { out[0] = 0.f; }
}

// ---------- kernel 2: persistent fused BiLSTM ----------
// 128 WGs: dir(2) x batch-half(2) x gate-slice(32).  256 threads.
// Overlap schedule (issue -> compute -> vm_drain -> use for every asm load):
//  P0 issue flag load | P1 x-MFMA 0..3 | P2 drain+flag-check | P3 issue h
//  loads, x-MFMA 4..7, drain, stage h_s | P4 x[t+1] prefetch + h-MFMAs |
//  P5 x->LDS | P6 update, hs store (plain), h store (sc1), drain, publish.
__global__ void __launch_bounds__(256, 1) lstm_kernel(
    const ushort_t* __restrict__ x_bf, const ushort_t* __restrict__ Wih_bf,
    const ushort_t* __restrict__ Whh_bf, const float* __restrict__ biasf,
    const float* __restrict__ biasb, const float* __restrict__ c0,
    const int* __restrict__ mask, ushort_t* __restrict__ hglob,
    ushort_t* __restrict__ hs, int* __restrict__ bar) {

    __shared__ __align__(16) ushort_t x_s[2][32 * 264];
    __shared__ __align__(16) ushort_t h_s[32 * 520];
    __shared__ __align__(16) float gates_s[64 * 33];

    const int tid = threadIdx.x;
    const int wid = blockIdx.x;
    const int dir = wid >> 6;
    const int bh  = (wid >> 5) & 1;
    const int gs  = wid & 31;
    const int j0  = gs * 16;
    const int group = dir * 2 + bh;
    int* flags = &bar[group * 1024];   // 32 peers, 32-int (128B) stride each

    const int lane = tid & 63;
    const int wv = tid >> 6;            // wave = gate type (i,f,g,o)
    const int qo = (lane >> 4) * 8;     // k-chunk offset in fragment
    const int ml = lane & 15;

    // persistent B fragments (W_ih: 8 ksteps, W_hh: 16 ksteps) in VGPRs
    const int grow = wv * 512 + j0 + ml;   // global gate row 0..2047
    short8 bxf[8], bhf[16];
    {
        const ushort_t* wr = Wih_bf + (size_t)dir * G4 * En + (size_t)grow * En + qo;
        #pragma unroll
        for (int ks = 0; ks < 8; ++ks) bxf[ks] = *(const short8*)(wr + ks * 32);
        const ushort_t* wr2 = Whh_bf + (size_t)dir * G4 * Hn + (size_t)grow * Hn + qo;
        #pragma unroll
        for (int ks = 0; ks < 16; ++ks) bhf[ks] = *(const short8*)(wr2 + ks * 32);
    }
    const float bv = (dir ? biasb : biasf)[grow];

    // update-phase mapping: thread -> (2 consecutive j, one batch) => one 4B store
    const int jp = (tid & 7) * 2;
    const int bl = tid >> 3;
    const int bg = bh * 32 + bl;
    float creg[2];
    #pragma unroll
    for (int r = 0; r < 2; ++r)
        creg[r] = c0[(size_t)dir * Bn * Hn + (size_t)bg * Hn + j0 + jp + r];

    const ushort_t* xbase = x_bf + (size_t)bh * 32 * En;
    ushort_t* hgbase = hglob + (size_t)dir * 2 * Bn * Hn + (size_t)bh * 32 * Hn;

    // x[t0] prefetch + LDS write (buffer 0)
    uint4 xreg[4];
    {
        const int t0 = dir ? (Tn - 1) : 0;
        const uint4* g4 = (const uint4*)(xbase + (size_t)t0 * Bn * En);
        #pragma unroll
        for (int k = 0; k < 4; ++k) xreg[k] = g4[tid + k * 256];
        #pragma unroll
        for (int k = 0; k < 4; ++k) {
            int c16 = tid + k * 256;
            int row = c16 >> 5, col = c16 & 31;
            *(uint4*)&x_s[0][row * 264 + col * 8] = xreg[k];
        }
    }
    // P1 reads x_s[0] across threads at s=0: barrier-separate the staging.
    __syncthreads();

    for (int s = 0; s < Tn; ++s) {
        const int t = dir ? (Tn - 1 - s) : s;
        const int cur = s & 1, nxt = cur ^ 1;

        // P0: pre-issue peer-flag load (in flight across P1); mask load
        int fv = 0x7fffffff;
        if (tid < 32) fv = gload4_sc1(&flags[tid * 32]);
        const int mv = mask[t * Bn + bg];

        // P1: x-part MFMAs, first half (hides flag-load flight)
        f32x4 acc0, acc1;
        #pragma unroll
        for (int r = 0; r < 4; ++r) { acc0[r] = bv; acc1[r] = bv; }
        const ushort_t* xr0 = &x_s[cur][ml * 264 + qo];
        const ushort_t* xr1 = &x_s[cur][(16 + ml) * 264 + qo];
        #pragma unroll
        for (int ks = 0; ks < 4; ++ks) {
            short8 a0 = *(const short8*)(xr0 + ks * 32);
            short8 a1 = *(const short8*)(xr1 + ks * 32);
            acc0 = __builtin_amdgcn_mfma_f32_16x16x32_bf16(a0, bxf[ks], acc0, 0, 0, 0);
            acc1 = __builtin_amdgcn_mfma_f32_16x16x32_bf16(a1, bxf[ks], acc1, 0, 0, 0);
        }

        // P2: drain (flag VGPR now valid), then check; fallback poll re-drains
        vm_drain();
        if (tid < 32 && tid != gs) {
            while (fv < s) {
                __builtin_amdgcn_s_sleep(1);
                fv = gload4_sc1(&flags[tid * 32]);
                vm_drain();
            }
        }
        __syncthreads();

        // P3: issue h loads; x-MFMA second half hides flight; drain; stage h_s
        {
            const ushort_t* hp0 = hgbase + (size_t)cur * Bn * Hn;
            uint4a hreg[8];
            #pragma unroll
            for (int k = 0; k < 8; ++k)
                hreg[k] = gload16_sc1(hp0 + (size_t)(tid + k * 256) * 8);
            #pragma unroll
            for (int ks = 4; ks < 8; ++ks) {
                short8 a0 = *(const short8*)(xr0 + ks * 32);
                short8 a1 = *(const short8*)(xr1 + ks * 32);
                acc0 = __builtin_amdgcn_mfma_f32_16x16x32_bf16(a0, bxf[ks], acc0, 0, 0, 0);
                acc1 = __builtin_amdgcn_mfma_f32_16x16x32_bf16(a1, bxf[ks], acc1, 0, 0, 0);
            }
            vm_drain();   // hreg VGPRs valid only after this
            #pragma unroll
            for (int k = 0; k < 8; ++k) {
                int c16 = tid + k * 256;
                int row = c16 >> 6, col = c16 & 63;
                *(uint4a*)&h_s[row * 520 + col * 8] = hreg[k];
            }
        }
        __syncthreads();

        // P4: issue x[t+1] prefetch (compiler-tracked; auto-waited at P5);
        //     h-part MFMAs; gates to LDS
        if (s < Tn - 1) {
            const int tn = dir ? (Tn - 2 - s) : (s + 1);
            const uint4* g4 = (const uint4*)(xbase + (size_t)tn * Bn * En);
            #pragma unroll
            for (int k = 0; k < 4; ++k) xreg[k] = g4[tid + k * 256];
        }
        {
            const ushort_t* hr0 = &h_s[ml * 520 + qo];
            const ushort_t* hr1 = &h_s[(16 + ml) * 520 + qo];
            #pragma unroll
            for (int ks = 0; ks < 16; ++ks) {
                short8 a0 = *(const short8*)(hr0 + ks * 32);
                short8 a1 = *(const short8*)(hr1 + ks * 32);
                acc0 = __builtin_amdgcn_mfma_f32_16x16x32_bf16(a0, bhf[ks], acc0, 0, 0, 0);
                acc1 = __builtin_amdgcn_mfma_f32_16x16x32_bf16(a1, bhf[ks], acc1, 0, 0, 0);
            }
            int nl = wv * 16 + ml;
            int br = (lane >> 4) * 4;
            #pragma unroll
            for (int r = 0; r < 4; ++r) {
                gates_s[nl * 33 + br + r]      = acc0[r];
                gates_s[nl * 33 + 16 + br + r] = acc1[r];
            }
        }
        __syncthreads();

        // P5: write next x into the other LDS buffer
        if (s < Tn - 1) {
            #pragma unroll
            for (int k = 0; k < 4; ++k) {
                int c16 = tid + k * 256;
                int row = c16 >> 5, col = c16 & 31;
                *(uint4*)&x_s[nxt][row * 264 + col * 8] = xreg[k];
            }
        }

        // P6: cell update; plain hs store; 4B sc1 h-store; drain; publish
        {
            ushort_t hu[2], su[2];
            #pragma unroll
            for (int r = 0; r < 2; ++r) {
                int j = jp + r;
                float iv = gates_s[j * 33 + bl];
                float fvv = gates_s[(16 + j) * 33 + bl];
                float gv = gates_s[(32 + j) * 33 + bl];
                float ov = gates_s[(48 + j) * 33 + bl];
                float cn = sigm(fvv) * creg[r] + sigm(iv) * tanh_(gv);
                float hn = sigm(ov) * tanh_(cn);
                float hp = bf2f(h_s[bl * 520 + j0 + j]);
                float h2, hsv;
                if (mv) { creg[r] = cn; h2 = hn; hsv = hn; }
                else    { h2 = hp; hsv = 0.f; }
                hu[r] = f2bf(h2);
                su[r] = f2bf(hsv);
            }
            *(uint_t*)&hs[((size_t)t * Bn + bg) * 1024 + dir * 512 + j0 + jp] =
                (uint_t)su[0] | ((uint_t)su[1] << 16);
            gstore4_sc1(&hgbase[(size_t)nxt * Bn * Hn + (size_t)bl * Hn + j0 + jp],
                        (uint_t)hu[0] | ((uint_t)hu[1] << 16));
        }
        vm_drain();
        __syncthreads();
        if (tid == 0) gstore4_sc1(&flags[gs * 32], (uint_t)(s + 1));
    }
}

// ---------- kernel 3: emission projection (wave per row, 16B hs loads) ----------
__global__ void emis_kernel(const ushort_t* __restrict__ hs, const float* __restrict__ Wout,
                            const float* __restrict__ bout, float* __restrict__ emis) {
    int row = blockIdx.x * 4 + (threadIdx.x >> 6);
    int lane = threadIdx.x & 63;
    const ushort_t* hr = hs + (size_t)row * 1024 + lane * 16;
    short8 h0v = *(const short8*)(hr);
    short8 h1v = *(const short8*)(hr + 8);
    float hv[16];
    #pragma unroll
    for (int j = 0; j < 8; ++j) {
        hv[j]     = bf2f((ushort_t)h0v[j]);
        hv[j + 8] = bf2f((ushort_t)h1v[j]);
    }
    float acc[6];
    #pragma unroll
    for (int n = 0; n < Nt; ++n) {
        const float* w = Wout + n * 1024 + lane * 16;
        float a = 0.f;
        #pragma unroll
        for (int j = 0; j < 16; ++j) a += hv[j] * w[j];
        acc[n] = a;
    }
    #pragma unroll
    for (int n = 0; n < Nt; ++n) {
        float v = acc[n];
        #pragma unroll
        for (int off = 32; off; off >>= 1) v += __shfl_down(v, off);
        if (lane == 0) emis[row * Nt + n] = v + bout[n];
    }
}

// ---------- kernel 4: CRF LLH (one wave per batch) ----------
__global__ void crf_kernel(const int* __restrict__ tags, const int* __restrict__ mask,
                           const float* __restrict__ emis, const float* __restrict__ trans,
                           const float* __restrict__ startt, const float* __restrict__ endt,
                           float* __restrict__ out) {
    int b = blockIdx.x;
    int lane = threadIdx.x;

    float part = 0.f;
    int mc = 0;
    for (int t = lane; t < Tn; t += 64) {
        int mv = mask[t * Bn + b];
        mc += mv;
        if (t >= 1) {
            int tp = tags[(t - 1) * Bn + b], tc = tags[t * Bn + b];
            part += (trans[tp * Nt + tc] + emis[(t * Bn + b) * Nt + tc]) * (float)mv;
        }
    }
    #pragma unroll
    for (int off = 32; off; off >>= 1) {
        part += __shfl_down(part, off);
        mc += __shfl_down(mc, off);
    }
    float num = 0.f;
    if (lane == 0) {
        int t0g = tags[b];
        num = startt[t0g] + emis[b * Nt + t0g] + part;
        int last = mc - 1;
        num += endt[tags[last * Bn + b]];
    }

    if (lane < Nt) {
        int j = lane;
        float tr[6];
        #pragma unroll
        for (int i = 0; i < Nt; ++i) tr[i] = trans[i * Nt + j];
        float score = startt[j] + emis[b * Nt + j];
        float e_nx = emis[(Bn + b) * Nt + j];
        int   m_nx = mask[Bn + b];
        for (int t = 1; t < Tn; ++t) {
            float e = e_nx;
            int mv = m_nx;
            if (t + 1 < Tn) {
                e_nx = emis[((t + 1) * Bn + b) * Nt + j];
                m_nx = mask[(t + 1) * Bn + b];
            }
            float v[6];
            float mx = -1e30f;
            #pragma unroll
            for (int i = 0; i < Nt; ++i) { v[i] = __shfl(score, i) + tr[i]; mx = fmaxf(mx, v[i]); }
            float sm = 0.f;
            #pragma unroll
            for (int i = 0; i < Nt; ++i) sm += __expf(v[i] - mx);
            float nxtv = mx + __logf(sm) + e;
            score = mv > 0 ? nxtv : score;
        }
        float fvv = score + endt[j];
        float m2 = fvv;
        #pragma unroll
        for (int i = 0; i < Nt; ++i) m2 = fmaxf(m2, __shfl(fvv, i));
        float s2 = 0.f;
        #pragma unroll
        for (int i = 0; i < Nt; ++i) s2 += __expf(__shfl(fvv, i) - m2);
        if (lane == 0) {
            float denom = m2 + __logf(s2);
            atomicAdd(out, num - denom);
        }
    }
}

extern "C" void kernel_launch(void* const* d_in, const int* in_sizes, int n_in,
                              void* d_out, int out_size, void* d_ws, size_t ws_size,
                              hipStream_t stream) {
    (void)in_sizes; (void)n_in; (void)out_size; (void)ws_size;
    const int*   sent  = (const int*)d_in[0];
    const int*   tags  = (const int*)d_in[1];
    const int*   mask  = (const int*)d_in[2];
    const float* h0    = (const float*)d_in[3];
    const float* c0    = (const float*)d_in[4];
    const float* embed = (const float*)d_in[5];
    const float* Wihf  = (const float*)d_in[6];
    const float* Whhf  = (const float*)d_in[7];
    const float* bf_   = (const float*)d_in[8];
    const float* Wihb  = (const float*)d_in[9];
    const float* Whhb  = (const float*)d_in[10];
    const float* bb_   = (const float*)d_in[11];
    const float* Wout  = (const float*)d_in[12];
    const float* bout  = (const float*)d_in[13];
    const float* trans = (const float*)d_in[14];
    const float* stt   = (const float*)d_in[15];
    const float* ent   = (const float*)d_in[16];
    float* out = (float*)d_out;
    char* ws = (char*)d_ws;

    ushort_t* x_bf   = (ushort_t*)(ws + OFF_XBF);
    ushort_t* Wih_bf = (ushort_t*)(ws + OFF_WIH);
    ushort_t* Whh_bf = (ushort_t*)(ws + OFF_WHH);
    ushort_t* hglob  = (ushort_t*)(ws + OFF_HG);
    ushort_t* hs     = (ushort_t*)(ws + OFF_HS);
    int*      bar    = (int*)(ws + OFF_BAR);
    float*    emis   = (float*)(ws + OFF_EMIS);

    prep_kernel<<<7313, 256, 0, stream>>>(sent, embed, Wihf, Whhf, Wihb, Whhb,
                                          h0, out, x_bf, Wih_bf, Whh_bf, hglob, bar);
    lstm_kernel<<<128, 256, 0, stream>>>(x_bf, Wih_bf, Whh_bf, bf_, bb_, c0,
                                         mask, hglob, hs, bar);
    emis_kernel<<<4096, 256, 0, stream>>>(hs, Wout, bout, emis);
    crf_kernel<<<64, 64, 0, stream>>>(tags, mask, emis, trans, stt, ent, out);
}